// Round 2
// baseline (7007.362 us; speedup 1.0000x reference)
//
#include <hip/hip_runtime.h>
#include <hip/hip_bf16.h>

// ---------------------------------------------------------------------------
// EncoderLayer (round 2): correctness-first + runtime dtype detection.
// B=2, S=4096, D=512, H=8, DK=64, DFF=2048.
// Pipeline: detect dtype -> convert inputs to canonical bf16 -> qkv gemm x3
// -> flash attention -> wo gemm -> LN1 -> ffn1 -> ffn2 -> LN2 -> out
// (written as bf16 or fp32 per detected dtype).
// ---------------------------------------------------------------------------

typedef unsigned short u16;
typedef __attribute__((ext_vector_type(4))) u16 u16x4;
typedef __attribute__((ext_vector_type(8))) u16 u16x8;

#define CB 2
#define CS 4096
#define CD 512
#define CH 8
#define CDK 64
#define CDFF 2048

__device__ __forceinline__ float bf2f(u16 u) {
    union { unsigned int i; float f; } c;
    c.i = ((unsigned int)u) << 16;
    return c.f;
}

__device__ __forceinline__ u16 f2bf(float f) {
    unsigned int x = __float_as_uint(f);
    unsigned int r = (x + 0x7fffu + ((x >> 16) & 1u)) >> 16;  // RNE
    return (u16)r;
}

// ---------------------------------------------------------------------------
// Dtype detection: interpret x's u32 words; the LOW u16 of each word is
//  - a genuine bf16 element (~N(0,1)) if the tensor is bf16-packed, or
//  - random fp32 mantissa bits if the tensor is fp32.
// Count "sane bf16" low halves (zero or exponent in [96,159] ~ 2^-31..2^32).
// bf16 data: ~100% sane. fp32 data: ~25% sane. flag=1 -> bf16, 0 -> fp32.
// ---------------------------------------------------------------------------
__global__ void detect_dtype(const unsigned int* __restrict__ xw, int* __restrict__ flag) {
    __shared__ int red[256];
    int sane = 0;
    for (int i = threadIdx.x; i < 2048; i += 256) {
        unsigned int w = xw[i];
        unsigned int lo = w & 0xFFFFu;
        unsigned int e = (lo >> 7) & 0xFFu;
        if (lo == 0u || lo == 0x8000u || (e >= 96u && e <= 159u)) sane++;
    }
    red[threadIdx.x] = sane;
    __syncthreads();
    for (int s = 128; s > 0; s >>= 1) {
        if ((int)threadIdx.x < s) red[threadIdx.x] += red[threadIdx.x + s];
        __syncthreads();
    }
    if (threadIdx.x == 0) *flag = (red[0] >= 1843) ? 1 : 0;
}

// Convert one tensor (bf16 pass-through or fp32 -> bf16) into ws.
__global__ __launch_bounds__(256) void convert_bf16(
    const void* __restrict__ src, u16* __restrict__ dst, int n,
    const int* __restrict__ flag)
{
    const bool isbf = (*flag != 0);
    int i = blockIdx.x * 256 + threadIdx.x;
    const int stride = gridDim.x * 256;
    if (isbf) {
        const u16* s = (const u16*)src;
        for (; i < n; i += stride) dst[i] = s[i];
    } else {
        const float* s = (const float*)src;
        for (; i < n; i += stride) dst[i] = f2bf(s[i]);
    }
}

// ---------------------------------------------------------------------------
// Tiled GEMM: C[M,N] = A[M,K] * B[K,N]  (bf16 in, fp32 accum, bf16 out)
// BM=BN=64, BK=16, 256 threads, 4x4 per thread.
// ---------------------------------------------------------------------------
#define F_SPLIT 1
#define F_BIAS  2
#define F_RELU  4

template <int FLAGS>
__global__ __launch_bounds__(256) void gemm_bf16(
    const u16* __restrict__ A, const u16* __restrict__ Bw,
    const u16* __restrict__ bias, u16* __restrict__ C,
    int M, int N, int K)
{
    __shared__ float As[16][64];   // [k][m]
    __shared__ float Bs[16][64];   // [k][n]

    const int tid = threadIdx.x;
    const int tx = tid & 15;
    const int ty = tid >> 4;
    const int row0 = blockIdx.y * 64;
    const int col0 = blockIdx.x * 64;

    const int arow = tid >> 2;
    const int acol = (tid & 3) * 4;
    const int brow = tid >> 4;
    const int bcol = (tid & 15) * 4;

    float acc[4][4] = {};

    for (int k0 = 0; k0 < K; k0 += 16) {
        u16x4 av = *(const u16x4*)(A + (size_t)(row0 + arow) * K + k0 + acol);
        u16x4 bv = *(const u16x4*)(Bw + (size_t)(k0 + brow) * N + col0 + bcol);
        __syncthreads();
        As[acol + 0][arow] = bf2f(av[0]);
        As[acol + 1][arow] = bf2f(av[1]);
        As[acol + 2][arow] = bf2f(av[2]);
        As[acol + 3][arow] = bf2f(av[3]);
        *(float4*)&Bs[brow][bcol] =
            make_float4(bf2f(bv[0]), bf2f(bv[1]), bf2f(bv[2]), bf2f(bv[3]));
        __syncthreads();
#pragma unroll
        for (int kk = 0; kk < 16; kk++) {
            float a[4], b[4];
#pragma unroll
            for (int i = 0; i < 4; i++) a[i] = As[kk][ty * 4 + i];
#pragma unroll
            for (int j = 0; j < 4; j++) b[j] = Bs[kk][tx * 4 + j];
#pragma unroll
            for (int i = 0; i < 4; i++)
#pragma unroll
                for (int j = 0; j < 4; j++) acc[i][j] += a[i] * b[j];
        }
    }

#pragma unroll
    for (int i = 0; i < 4; i++) {
        const int mm = row0 + ty * 4 + i;
        const int nn0 = col0 + tx * 4;
        size_t idx;
        if (FLAGS & F_SPLIT) {
            const int bb = mm >> 12;
            const int ss = mm & 4095;
            const int hh = nn0 >> 6;
            const int dk = nn0 & 63;
            idx = (((size_t)(bb * CH + hh)) * CS + ss) * CDK + dk;
        } else {
            idx = (size_t)mm * N + nn0;
        }
        u16x4 ov;
#pragma unroll
        for (int j = 0; j < 4; j++) {
            float val = acc[i][j];
            if (FLAGS & F_BIAS) val += bf2f(bias[nn0 + j]);
            if (FLAGS & F_RELU) val = fmaxf(val, 0.f);
            ov[j] = f2bf(val);
        }
        *(u16x4*)(C + idx) = ov;
    }
}

// ---------------------------------------------------------------------------
// Flash attention: grid (S/128, B*H), 128 threads, one thread = one query.
// ---------------------------------------------------------------------------
__global__ void flash_attn(const u16* __restrict__ Qb, const u16* __restrict__ Kb,
                           const u16* __restrict__ Vb, const int* __restrict__ mask,
                           u16* __restrict__ ctx)
{
    __shared__ float Ks[64][CDK];
    __shared__ float Vs[64][CDK];
    __shared__ int msk[64];

    const int bh = blockIdx.y;
    const int b = bh / CH;
    const int h = bh % CH;
    const int qi = blockIdx.x * 128 + threadIdx.x;

    const u16* qp = Qb + ((size_t)bh * CS + qi) * CDK;
    float qr[CDK];
#pragma unroll
    for (int d = 0; d < CDK; d += 8) {
        u16x8 t8 = *(const u16x8*)(qp + d);
#pragma unroll
        for (int j = 0; j < 8; j++) qr[d + j] = bf2f(t8[j]) * 0.125f;
    }

    float o[CDK] = {};
    float mx = -1e30f, l = 0.f;

    for (int t = 0; t < CS; t += 64) {
        const u16* kp = Kb + ((size_t)bh * CS + t) * CDK;
        const u16* vp = Vb + ((size_t)bh * CS + t) * CDK;
        __syncthreads();
        for (int i = threadIdx.x; i < 64 * CDK / 4; i += 128) {
            u16x4 kv = ((const u16x4*)kp)[i];
            u16x4 vv = ((const u16x4*)vp)[i];
            ((float4*)Ks)[i] = make_float4(bf2f(kv[0]), bf2f(kv[1]), bf2f(kv[2]), bf2f(kv[3]));
            ((float4*)Vs)[i] = make_float4(bf2f(vv[0]), bf2f(vv[1]), bf2f(vv[2]), bf2f(vv[3]));
        }
        if (threadIdx.x < 64) msk[threadIdx.x] = mask[b * CS + t + threadIdx.x];
        __syncthreads();

        for (int kk = 0; kk < 64; kk++) {
            float s = 0.f;
#pragma unroll
            for (int d = 0; d < CDK; d++) s += qr[d] * Ks[kk][d];
            if (msk[kk] == 0) s = -1e9f;
            if (s <= mx) {
                float p = __expf(s - mx);
                l += p;
#pragma unroll
                for (int d = 0; d < CDK; d++) o[d] += p * Vs[kk][d];
            } else {
                float sc = __expf(mx - s);
                mx = s;
                l = l * sc + 1.f;
#pragma unroll
                for (int d = 0; d < CDK; d++) o[d] = o[d] * sc + Vs[kk][d];
            }
        }
    }

    const float inv = 1.f / l;
    u16* cp = ctx + ((size_t)(b * CS + qi)) * CD + h * CDK;
#pragma unroll
    for (int d = 0; d < CDK; d += 4) {
        u16x4 ov;
        ov[0] = f2bf(o[d + 0] * inv);
        ov[1] = f2bf(o[d + 1] * inv);
        ov[2] = f2bf(o[d + 2] * inv);
        ov[3] = f2bf(o[d + 3] * inv);
        *(u16x4*)(cp + d) = ov;
    }
}

// ---------------------------------------------------------------------------
// Residual + LayerNorm. One wave per row (D=512, 8 elems/lane), 4 rows/block.
// outf != nullptr and *flag==0 -> write fp32 to outf; else bf16 to outb.
// ---------------------------------------------------------------------------
__global__ __launch_bounds__(256) void ln_kernel(
    const u16* __restrict__ xa, const u16* __restrict__ xb,
    const u16* __restrict__ g, const u16* __restrict__ be,
    u16* __restrict__ outb, float* __restrict__ outf,
    const int* __restrict__ flag)
{
    const int lane = threadIdx.x & 63;
    const int wave = threadIdx.x >> 6;
    const size_t row = (size_t)blockIdx.x * 4 + wave;
    const int c0 = lane * 8;

    u16x8 av = *(const u16x8*)(xa + row * CD + c0);
    u16x8 bv = *(const u16x8*)(xb + row * CD + c0);

    float v[8];
    float s1 = 0.f, s2 = 0.f;
#pragma unroll
    for (int e = 0; e < 8; e++) {
        v[e] = bf2f(av[e]) + bf2f(bv[e]);
        s1 += v[e];
        s2 += v[e] * v[e];
    }
#pragma unroll
    for (int off = 32; off > 0; off >>= 1) {
        s1 += __shfl_xor(s1, off, 64);
        s2 += __shfl_xor(s2, off, 64);
    }
    const float mu = s1 * (1.f / CD);
    const float var = fmaxf(s2 * (1.f / CD) - mu * mu, 0.f);
    const float r = rsqrtf(var + 1e-5f);

    u16x8 gv = *(const u16x8*)(g + c0);
    u16x8 ev = *(const u16x8*)(be + c0);
    float res[8];
#pragma unroll
    for (int e = 0; e < 8; e++)
        res[e] = (v[e] - mu) * r * bf2f(gv[e]) + bf2f(ev[e]);

    const int flg = *flag;
    const bool f32out = (outf != nullptr) && (flg == 0);
    if (f32out) {
        float4 o0 = make_float4(res[0], res[1], res[2], res[3]);
        float4 o1 = make_float4(res[4], res[5], res[6], res[7]);
        *(float4*)(outf + row * CD + c0) = o0;
        *(float4*)(outf + row * CD + c0 + 4) = o1;
    } else {
        u16x8 ov;
#pragma unroll
        for (int e = 0; e < 8; e++) ov[e] = f2bf(res[e]);
        *(u16x8*)(outb + row * CD + c0) = ov;
    }
}

// ---------------------------------------------------------------------------

extern "C" void kernel_launch(void* const* d_in, const int* in_sizes, int n_in,
                              void* d_out, int out_size, void* d_ws, size_t ws_size,
                              hipStream_t stream)
{
    const void* x_raw   = d_in[0];
    const int*  mask    = (const int*)d_in[1];
    const void* wq_raw  = d_in[2];
    const void* wk_raw  = d_in[3];
    const void* wv_raw  = d_in[4];
    const void* wo_raw  = d_in[5];
    const void* w1_raw  = d_in[6];
    const void* b1_raw  = d_in[7];
    const void* w2_raw  = d_in[8];
    const void* b2_raw  = d_in[9];
    const void* g1_raw  = d_in[10];
    const void* be1_raw = d_in[11];
    const void* g2_raw  = d_in[12];
    const void* be2_raw = d_in[13];

    const size_t NX = (size_t)CB * CS * CD;      // 4,194,304
    const size_t WSZ = (size_t)CD * CD;          // 262,144
    const size_t W1SZ = (size_t)CD * CDFF;       // 1,048,576

    // ws layout (u16 units)
    u16* ws = (u16*)d_ws;
    int* flag = (int*)d_ws;
    u16* base = ws + 1024;
    u16* xc  = base;
    u16* q   = base + 1 * NX;
    u16* k   = base + 2 * NX;
    u16* v   = base + 3 * NX;
    u16* ctx = base + 4 * NX;
    u16* att = base + 5 * NX;
    u16* x1  = base + 6 * NX;
    u16* ffo = base + 7 * NX;
    u16* ffh = base + 8 * NX;          // 4*NX
    u16* wt  = base + 12 * NX;
    u16* wqc = wt;
    u16* wkc = wqc + WSZ;
    u16* wvc = wkc + WSZ;
    u16* woc = wvc + WSZ;
    u16* w1c = woc + WSZ;
    u16* w2c = w1c + W1SZ;
    u16* b1c = w2c + W1SZ;
    u16* b2c = b1c + CDFF;
    u16* g1c = b2c + CD;
    u16* be1c = g1c + CD;
    u16* g2c = be1c + CD;
    u16* be2c = g2c + CD;
    u16* wend = be2c + CD;

    const size_t need = (size_t)(wend - ws) * sizeof(u16);
    if (ws_size < need) return;  // distinguishable signature: absmax ~5.0

    detect_dtype<<<1, 256, 0, stream>>>((const unsigned int*)x_raw, flag);

    auto conv = [&](const void* src, u16* dst, int n) {
        int blocks = (n + 256 * 8 - 1) / (256 * 8);
        if (blocks > 1024) blocks = 1024;
        if (blocks < 1) blocks = 1;
        convert_bf16<<<blocks, 256, 0, stream>>>(src, dst, n, flag);
    };
    conv(x_raw, xc, (int)NX);
    conv(wq_raw, wqc, (int)WSZ);
    conv(wk_raw, wkc, (int)WSZ);
    conv(wv_raw, wvc, (int)WSZ);
    conv(wo_raw, woc, (int)WSZ);
    conv(w1_raw, w1c, (int)W1SZ);
    conv(w2_raw, w2c, (int)W1SZ);
    conv(b1_raw, b1c, CDFF);
    conv(b2_raw, b2c, CD);
    conv(g1_raw, g1c, CD);
    conv(be1_raw, be1c, CD);
    conv(g2_raw, g2c, CD);
    conv(be2_raw, be2c, CD);

    const int M = CB * CS;  // 8192

    dim3 gProj(CD / 64, M / 64);
    gemm_bf16<F_SPLIT><<<gProj, 256, 0, stream>>>(xc, wqc, nullptr, q, M, CD, CD);
    gemm_bf16<F_SPLIT><<<gProj, 256, 0, stream>>>(xc, wkc, nullptr, k, M, CD, CD);
    gemm_bf16<F_SPLIT><<<gProj, 256, 0, stream>>>(xc, wvc, nullptr, v, M, CD, CD);

    flash_attn<<<dim3(CS / 128, CB * CH), 128, 0, stream>>>(q, k, v, mask, ctx);

    gemm_bf16<0><<<gProj, 256, 0, stream>>>(ctx, woc, nullptr, att, M, CD, CD);

    ln_kernel<<<dim3(M / 4), 256, 0, stream>>>(xc, att, g1c, be1c, x1, nullptr, flag);

    gemm_bf16<F_BIAS | F_RELU><<<dim3(CDFF / 64, M / 64), 256, 0, stream>>>(
        x1, w1c, b1c, ffh, M, CDFF, CD);
    gemm_bf16<F_BIAS><<<gProj, 256, 0, stream>>>(ffh, w2c, b2c, ffo, M, CD, CDFF);

    ln_kernel<<<dim3(M / 4), 256, 0, stream>>>(x1, ffo, g2c, be2c,
                                               (u16*)d_out, (float*)d_out, flag);
}

// Round 3
// 2964.043 us; speedup vs baseline: 2.3641x; 2.3641x over previous
//
#include <hip/hip_runtime.h>
#include <hip/hip_bf16.h>

// ---------------------------------------------------------------------------
// EncoderLayer (round 3): fix flash_attn register spill (launch_bounds) +
// vectorize its LDS/compute. Pipeline otherwise unchanged from round 2.
// B=2, S=4096, D=512, H=8, DK=64, DFF=2048. fp32 inputs -> canonical bf16.
// ---------------------------------------------------------------------------

typedef unsigned short u16;
typedef __attribute__((ext_vector_type(4))) u16 u16x4;
typedef __attribute__((ext_vector_type(8))) u16 u16x8;
typedef __attribute__((ext_vector_type(4))) float f32x4;

#define CB 2
#define CS 4096
#define CD 512
#define CH 8
#define CDK 64
#define CDFF 2048

__device__ __forceinline__ float bf2f(u16 u) {
    union { unsigned int i; float f; } c;
    c.i = ((unsigned int)u) << 16;
    return c.f;
}

__device__ __forceinline__ u16 f2bf(float f) {
    unsigned int x = __float_as_uint(f);
    unsigned int r = (x + 0x7fffu + ((x >> 16) & 1u)) >> 16;  // RNE
    return (u16)r;
}

// ---------------------------------------------------------------------------
// Dtype detection (bf16-packed vs fp32): see round-2 notes. flag=1 -> bf16.
// ---------------------------------------------------------------------------
__global__ void detect_dtype(const unsigned int* __restrict__ xw, int* __restrict__ flag) {
    __shared__ int red[256];
    int sane = 0;
    for (int i = threadIdx.x; i < 2048; i += 256) {
        unsigned int w = xw[i];
        unsigned int lo = w & 0xFFFFu;
        unsigned int e = (lo >> 7) & 0xFFu;
        if (lo == 0u || lo == 0x8000u || (e >= 96u && e <= 159u)) sane++;
    }
    red[threadIdx.x] = sane;
    __syncthreads();
    for (int s = 128; s > 0; s >>= 1) {
        if ((int)threadIdx.x < s) red[threadIdx.x] += red[threadIdx.x + s];
        __syncthreads();
    }
    if (threadIdx.x == 0) *flag = (red[0] >= 1843) ? 1 : 0;
}

__global__ __launch_bounds__(256) void convert_bf16(
    const void* __restrict__ src, u16* __restrict__ dst, int n,
    const int* __restrict__ flag)
{
    const bool isbf = (*flag != 0);
    int i = blockIdx.x * 256 + threadIdx.x;
    const int stride = gridDim.x * 256;
    if (isbf) {
        const u16* s = (const u16*)src;
        for (; i < n; i += stride) dst[i] = s[i];
    } else {
        const float* s = (const float*)src;
        for (; i < n; i += stride) dst[i] = f2bf(s[i]);
    }
}

// ---------------------------------------------------------------------------
// Tiled GEMM: C[M,N] = A[M,K] * B[K,N]  (bf16 in, fp32 accum, bf16 out)
// BM=BN=64, BK=16, 256 threads, 4x4 per thread.
// ---------------------------------------------------------------------------
#define F_SPLIT 1
#define F_BIAS  2
#define F_RELU  4

template <int FLAGS>
__global__ __launch_bounds__(256) void gemm_bf16(
    const u16* __restrict__ A, const u16* __restrict__ Bw,
    const u16* __restrict__ bias, u16* __restrict__ C,
    int M, int N, int K)
{
    __shared__ float As[16][64];   // [k][m]
    __shared__ float Bs[16][64];   // [k][n]

    const int tid = threadIdx.x;
    const int tx = tid & 15;
    const int ty = tid >> 4;
    const int row0 = blockIdx.y * 64;
    const int col0 = blockIdx.x * 64;

    const int arow = tid >> 2;
    const int acol = (tid & 3) * 4;
    const int brow = tid >> 4;
    const int bcol = (tid & 15) * 4;

    float acc[4][4] = {};

    for (int k0 = 0; k0 < K; k0 += 16) {
        u16x4 av = *(const u16x4*)(A + (size_t)(row0 + arow) * K + k0 + acol);
        u16x4 bv = *(const u16x4*)(Bw + (size_t)(k0 + brow) * N + col0 + bcol);
        __syncthreads();
        As[acol + 0][arow] = bf2f(av[0]);
        As[acol + 1][arow] = bf2f(av[1]);
        As[acol + 2][arow] = bf2f(av[2]);
        As[acol + 3][arow] = bf2f(av[3]);
        *(float4*)&Bs[brow][bcol] =
            make_float4(bf2f(bv[0]), bf2f(bv[1]), bf2f(bv[2]), bf2f(bv[3]));
        __syncthreads();
#pragma unroll
        for (int kk = 0; kk < 16; kk++) {
            float a[4], b[4];
#pragma unroll
            for (int i = 0; i < 4; i++) a[i] = As[kk][ty * 4 + i];
#pragma unroll
            for (int j = 0; j < 4; j++) b[j] = Bs[kk][tx * 4 + j];
#pragma unroll
            for (int i = 0; i < 4; i++)
#pragma unroll
                for (int j = 0; j < 4; j++) acc[i][j] += a[i] * b[j];
        }
    }

#pragma unroll
    for (int i = 0; i < 4; i++) {
        const int mm = row0 + ty * 4 + i;
        const int nn0 = col0 + tx * 4;
        size_t idx;
        if (FLAGS & F_SPLIT) {
            const int bb = mm >> 12;
            const int ss = mm & 4095;
            const int hh = nn0 >> 6;
            const int dk = nn0 & 63;
            idx = (((size_t)(bb * CH + hh)) * CS + ss) * CDK + dk;
        } else {
            idx = (size_t)mm * N + nn0;
        }
        u16x4 ov;
#pragma unroll
        for (int j = 0; j < 4; j++) {
            float val = acc[i][j];
            if (FLAGS & F_BIAS) val += bf2f(bias[nn0 + j]);
            if (FLAGS & F_RELU) val = fmaxf(val, 0.f);
            ov[j] = f2bf(val);
        }
        *(u16x4*)(C + idx) = ov;
    }
}

// ---------------------------------------------------------------------------
// Flash attention: grid (S/128, B*H), 128 threads, one thread = one query.
// __launch_bounds__(128,2): VGPR cap 256 so qr[16]+o[16] f32x4 stay in regs
// (round-2 version spilled to scratch at the default 64-VGPR cap -> 6.3 ms).
// ---------------------------------------------------------------------------
__global__ __launch_bounds__(128, 2) void flash_attn(
    const u16* __restrict__ Qb, const u16* __restrict__ Kb,
    const u16* __restrict__ Vb, const int* __restrict__ mask,
    u16* __restrict__ ctx)
{
    __shared__ f32x4 Ks[64][CDK / 4];   // 16 f32x4 per key row
    __shared__ f32x4 Vs[64][CDK / 4];
    __shared__ int msk[64];

    const int bh = blockIdx.y;
    const int b = bh / CH;
    const int h = bh % CH;
    const int qi = blockIdx.x * 128 + threadIdx.x;

    const u16* qp = Qb + ((size_t)bh * CS + qi) * CDK;
    f32x4 qr[16];
#pragma unroll
    for (int d = 0; d < 16; d += 2) {
        u16x8 t8 = *(const u16x8*)(qp + d * 4);
        qr[d + 0] = f32x4{bf2f(t8[0]), bf2f(t8[1]), bf2f(t8[2]), bf2f(t8[3])} * 0.125f;
        qr[d + 1] = f32x4{bf2f(t8[4]), bf2f(t8[5]), bf2f(t8[6]), bf2f(t8[7])} * 0.125f;
    }

    f32x4 o[16];
#pragma unroll
    for (int d = 0; d < 16; d++) o[d] = f32x4{0.f, 0.f, 0.f, 0.f};
    float mx = -1e30f, l = 0.f;

    for (int t = 0; t < CS; t += 64) {
        const u16* kp = Kb + ((size_t)bh * CS + t) * CDK;
        const u16* vp = Vb + ((size_t)bh * CS + t) * CDK;
        __syncthreads();
        // stage 64x64 K and V tiles: 128 threads x 4 u16x8 each
        for (int i = threadIdx.x; i < 64 * CDK / 8; i += 128) {
            u16x8 kv = ((const u16x8*)kp)[i];
            u16x8 vv = ((const u16x8*)vp)[i];
            ((f32x4*)Ks)[i * 2 + 0] = f32x4{bf2f(kv[0]), bf2f(kv[1]), bf2f(kv[2]), bf2f(kv[3])};
            ((f32x4*)Ks)[i * 2 + 1] = f32x4{bf2f(kv[4]), bf2f(kv[5]), bf2f(kv[6]), bf2f(kv[7])};
            ((f32x4*)Vs)[i * 2 + 0] = f32x4{bf2f(vv[0]), bf2f(vv[1]), bf2f(vv[2]), bf2f(vv[3])};
            ((f32x4*)Vs)[i * 2 + 1] = f32x4{bf2f(vv[4]), bf2f(vv[5]), bf2f(vv[6]), bf2f(vv[7])};
        }
        if (threadIdx.x < 64) msk[threadIdx.x] = mask[b * CS + t + threadIdx.x];
        __syncthreads();

        for (int kk = 0; kk < 64; kk++) {
            f32x4 sv = f32x4{0.f, 0.f, 0.f, 0.f};
#pragma unroll
            for (int d = 0; d < 16; d++) sv += qr[d] * Ks[kk][d];
            float s = sv.x + sv.y + sv.z + sv.w;
            if (msk[kk] == 0) s = -1e9f;
            if (s <= mx) {
                float p = __expf(s - mx);
                l += p;
#pragma unroll
                for (int d = 0; d < 16; d++) o[d] += p * Vs[kk][d];
            } else {
                float sc = __expf(mx - s);
                mx = s;
                l = l * sc + 1.f;
#pragma unroll
                for (int d = 0; d < 16; d++) o[d] = o[d] * sc + Vs[kk][d];
            }
        }
    }

    const float inv = 1.f / l;
    u16* cp = ctx + ((size_t)(b * CS + qi)) * CD + h * CDK;
#pragma unroll
    for (int d = 0; d < 16; d += 2) {
        f32x4 a = o[d] * inv;
        f32x4 c = o[d + 1] * inv;
        u16x8 ov;
        ov[0] = f2bf(a.x); ov[1] = f2bf(a.y); ov[2] = f2bf(a.z); ov[3] = f2bf(a.w);
        ov[4] = f2bf(c.x); ov[5] = f2bf(c.y); ov[6] = f2bf(c.z); ov[7] = f2bf(c.w);
        *(u16x8*)(cp + d * 4) = ov;
    }
}

// ---------------------------------------------------------------------------
// Residual + LayerNorm. One wave per row (D=512, 8 elems/lane), 4 rows/block.
// outf != nullptr and *flag==0 -> write fp32 to outf; else bf16 to outb.
// ---------------------------------------------------------------------------
__global__ __launch_bounds__(256) void ln_kernel(
    const u16* __restrict__ xa, const u16* __restrict__ xb,
    const u16* __restrict__ g, const u16* __restrict__ be,
    u16* __restrict__ outb, float* __restrict__ outf,
    const int* __restrict__ flag)
{
    const int lane = threadIdx.x & 63;
    const int wave = threadIdx.x >> 6;
    const size_t row = (size_t)blockIdx.x * 4 + wave;
    const int c0 = lane * 8;

    u16x8 av = *(const u16x8*)(xa + row * CD + c0);
    u16x8 bv = *(const u16x8*)(xb + row * CD + c0);

    float v[8];
    float s1 = 0.f, s2 = 0.f;
#pragma unroll
    for (int e = 0; e < 8; e++) {
        v[e] = bf2f(av[e]) + bf2f(bv[e]);
        s1 += v[e];
        s2 += v[e] * v[e];
    }
#pragma unroll
    for (int off = 32; off > 0; off >>= 1) {
        s1 += __shfl_xor(s1, off, 64);
        s2 += __shfl_xor(s2, off, 64);
    }
    const float mu = s1 * (1.f / CD);
    const float var = fmaxf(s2 * (1.f / CD) - mu * mu, 0.f);
    const float r = rsqrtf(var + 1e-5f);

    u16x8 gv = *(const u16x8*)(g + c0);
    u16x8 ev = *(const u16x8*)(be + c0);
    float res[8];
#pragma unroll
    for (int e = 0; e < 8; e++)
        res[e] = (v[e] - mu) * r * bf2f(gv[e]) + bf2f(ev[e]);

    const int flg = *flag;
    const bool f32out = (outf != nullptr) && (flg == 0);
    if (f32out) {
        float4 o0 = make_float4(res[0], res[1], res[2], res[3]);
        float4 o1 = make_float4(res[4], res[5], res[6], res[7]);
        *(float4*)(outf + row * CD + c0) = o0;
        *(float4*)(outf + row * CD + c0 + 4) = o1;
    } else {
        u16x8 ov;
#pragma unroll
        for (int e = 0; e < 8; e++) ov[e] = f2bf(res[e]);
        *(u16x8*)(outb + row * CD + c0) = ov;
    }
}

// ---------------------------------------------------------------------------

extern "C" void kernel_launch(void* const* d_in, const int* in_sizes, int n_in,
                              void* d_out, int out_size, void* d_ws, size_t ws_size,
                              hipStream_t stream)
{
    const void* x_raw   = d_in[0];
    const int*  mask    = (const int*)d_in[1];
    const void* wq_raw  = d_in[2];
    const void* wk_raw  = d_in[3];
    const void* wv_raw  = d_in[4];
    const void* wo_raw  = d_in[5];
    const void* w1_raw  = d_in[6];
    const void* b1_raw  = d_in[7];
    const void* w2_raw  = d_in[8];
    const void* b2_raw  = d_in[9];
    const void* g1_raw  = d_in[10];
    const void* be1_raw = d_in[11];
    const void* g2_raw  = d_in[12];
    const void* be2_raw = d_in[13];

    const size_t NX = (size_t)CB * CS * CD;      // 4,194,304
    const size_t WSZ = (size_t)CD * CD;          // 262,144
    const size_t W1SZ = (size_t)CD * CDFF;       // 1,048,576

    u16* ws = (u16*)d_ws;
    int* flag = (int*)d_ws;
    u16* base = ws + 1024;
    u16* xc  = base;
    u16* q   = base + 1 * NX;
    u16* k   = base + 2 * NX;
    u16* v   = base + 3 * NX;
    u16* ctx = base + 4 * NX;
    u16* att = base + 5 * NX;
    u16* x1  = base + 6 * NX;
    u16* ffo = base + 7 * NX;
    u16* ffh = base + 8 * NX;          // 4*NX
    u16* wt  = base + 12 * NX;
    u16* wqc = wt;
    u16* wkc = wqc + WSZ;
    u16* wvc = wkc + WSZ;
    u16* woc = wvc + WSZ;
    u16* w1c = woc + WSZ;
    u16* w2c = w1c + W1SZ;
    u16* b1c = w2c + W1SZ;
    u16* b2c = b1c + CDFF;
    u16* g1c = b2c + CD;
    u16* be1c = g1c + CD;
    u16* g2c = be1c + CD;
    u16* be2c = g2c + CD;
    u16* wend = be2c + CD;

    const size_t need = (size_t)(wend - ws) * sizeof(u16);
    if (ws_size < need) return;

    detect_dtype<<<1, 256, 0, stream>>>((const unsigned int*)x_raw, flag);

    auto conv = [&](const void* src, u16* dst, int n) {
        int blocks = (n + 256 * 8 - 1) / (256 * 8);
        if (blocks > 1024) blocks = 1024;
        if (blocks < 1) blocks = 1;
        convert_bf16<<<blocks, 256, 0, stream>>>(src, dst, n, flag);
    };
    conv(x_raw, xc, (int)NX);
    conv(wq_raw, wqc, (int)WSZ);
    conv(wk_raw, wkc, (int)WSZ);
    conv(wv_raw, wvc, (int)WSZ);
    conv(wo_raw, woc, (int)WSZ);
    conv(w1_raw, w1c, (int)W1SZ);
    conv(w2_raw, w2c, (int)W1SZ);
    conv(b1_raw, b1c, CDFF);
    conv(b2_raw, b2c, CD);
    conv(g1_raw, g1c, CD);
    conv(be1_raw, be1c, CD);
    conv(g2_raw, g2c, CD);
    conv(be2_raw, be2c, CD);

    const int M = CB * CS;  // 8192

    dim3 gProj(CD / 64, M / 64);
    gemm_bf16<F_SPLIT><<<gProj, 256, 0, stream>>>(xc, wqc, nullptr, q, M, CD, CD);
    gemm_bf16<F_SPLIT><<<gProj, 256, 0, stream>>>(xc, wkc, nullptr, k, M, CD, CD);
    gemm_bf16<F_SPLIT><<<gProj, 256, 0, stream>>>(xc, wvc, nullptr, v, M, CD, CD);

    flash_attn<<<dim3(CS / 128, CB * CH), 128, 0, stream>>>(q, k, v, mask, ctx);

    gemm_bf16<0><<<gProj, 256, 0, stream>>>(ctx, woc, nullptr, att, M, CD, CD);

    ln_kernel<<<dim3(M / 4), 256, 0, stream>>>(xc, att, g1c, be1c, x1, nullptr, flag);

    gemm_bf16<F_BIAS | F_RELU><<<dim3(CDFF / 64, M / 64), 256, 0, stream>>>(
        x1, w1c, b1c, ffh, M, CDFF, CD);
    gemm_bf16<F_BIAS><<<gProj, 256, 0, stream>>>(ffh, w2c, b2c, ffo, M, CD, CDFF);

    ln_kernel<<<dim3(M / 4), 256, 0, stream>>>(x1, ffo, g2c, be2c,
                                               (u16*)d_out, (float*)d_out, flag);
}

// Round 4
// 1010.845 us; speedup vs baseline: 6.9322x; 2.9322x over previous
//
#include <hip/hip_runtime.h>
#include <hip/hip_bf16.h>

// ---------------------------------------------------------------------------
// EncoderLayer (round 4): MFMA flash attention (16x16x32 bf16), per m120
// pattern. GEMMs/LN unchanged from round 3 (next target).
// B=2, S=4096, D=512, H=8, DK=64, DFF=2048. fp32 inputs -> canonical bf16.
// ---------------------------------------------------------------------------

typedef unsigned short u16;
typedef __attribute__((ext_vector_type(4))) u16 u16x4;
typedef __attribute__((ext_vector_type(8))) u16 u16x8;
typedef __attribute__((ext_vector_type(4))) float f32x4;
typedef __attribute__((ext_vector_type(8))) short bf16x8;  // MFMA A/B frag

#define CB 2
#define CS 4096
#define CD 512
#define CH 8
#define CDK 64
#define CDFF 2048

__device__ __forceinline__ float bf2f(u16 u) {
    union { unsigned int i; float f; } c;
    c.i = ((unsigned int)u) << 16;
    return c.f;
}

__device__ __forceinline__ u16 f2bf(float f) {
    unsigned int x = __float_as_uint(f);
    unsigned int r = (x + 0x7fffu + ((x >> 16) & 1u)) >> 16;  // RNE
    return (u16)r;
}

// ---------------------------------------------------------------------------
// Dtype detection (bf16-packed vs fp32). flag=1 -> bf16.
// ---------------------------------------------------------------------------
__global__ void detect_dtype(const unsigned int* __restrict__ xw, int* __restrict__ flag) {
    __shared__ int red[256];
    int sane = 0;
    for (int i = threadIdx.x; i < 2048; i += 256) {
        unsigned int w = xw[i];
        unsigned int lo = w & 0xFFFFu;
        unsigned int e = (lo >> 7) & 0xFFu;
        if (lo == 0u || lo == 0x8000u || (e >= 96u && e <= 159u)) sane++;
    }
    red[threadIdx.x] = sane;
    __syncthreads();
    for (int s = 128; s > 0; s >>= 1) {
        if ((int)threadIdx.x < s) red[threadIdx.x] += red[threadIdx.x + s];
        __syncthreads();
    }
    if (threadIdx.x == 0) *flag = (red[0] >= 1843) ? 1 : 0;
}

__global__ __launch_bounds__(256) void convert_bf16(
    const void* __restrict__ src, u16* __restrict__ dst, int n,
    const int* __restrict__ flag)
{
    const bool isbf = (*flag != 0);
    int i = blockIdx.x * 256 + threadIdx.x;
    const int stride = gridDim.x * 256;
    if (isbf) {
        const u16* s = (const u16*)src;
        for (; i < n; i += stride) dst[i] = s[i];
    } else {
        const float* s = (const float*)src;
        for (; i < n; i += stride) dst[i] = f2bf(s[i]);
    }
}

// ---------------------------------------------------------------------------
// Tiled GEMM (vector-ALU, unchanged): C[M,N] = A[M,K]*B[K,N]
// ---------------------------------------------------------------------------
#define F_SPLIT 1
#define F_BIAS  2
#define F_RELU  4

template <int FLAGS>
__global__ __launch_bounds__(256) void gemm_bf16(
    const u16* __restrict__ A, const u16* __restrict__ Bw,
    const u16* __restrict__ bias, u16* __restrict__ C,
    int M, int N, int K)
{
    __shared__ float As[16][64];
    __shared__ float Bs[16][64];

    const int tid = threadIdx.x;
    const int tx = tid & 15;
    const int ty = tid >> 4;
    const int row0 = blockIdx.y * 64;
    const int col0 = blockIdx.x * 64;

    const int arow = tid >> 2;
    const int acol = (tid & 3) * 4;
    const int brow = tid >> 4;
    const int bcol = (tid & 15) * 4;

    float acc[4][4] = {};

    for (int k0 = 0; k0 < K; k0 += 16) {
        u16x4 av = *(const u16x4*)(A + (size_t)(row0 + arow) * K + k0 + acol);
        u16x4 bv = *(const u16x4*)(Bw + (size_t)(k0 + brow) * N + col0 + bcol);
        __syncthreads();
        As[acol + 0][arow] = bf2f(av[0]);
        As[acol + 1][arow] = bf2f(av[1]);
        As[acol + 2][arow] = bf2f(av[2]);
        As[acol + 3][arow] = bf2f(av[3]);
        *(float4*)&Bs[brow][bcol] =
            make_float4(bf2f(bv[0]), bf2f(bv[1]), bf2f(bv[2]), bf2f(bv[3]));
        __syncthreads();
#pragma unroll
        for (int kk = 0; kk < 16; kk++) {
            float a[4], b[4];
#pragma unroll
            for (int i = 0; i < 4; i++) a[i] = As[kk][ty * 4 + i];
#pragma unroll
            for (int j = 0; j < 4; j++) b[j] = Bs[kk][tx * 4 + j];
#pragma unroll
            for (int i = 0; i < 4; i++)
#pragma unroll
                for (int j = 0; j < 4; j++) acc[i][j] += a[i] * b[j];
        }
    }

#pragma unroll
    for (int i = 0; i < 4; i++) {
        const int mm = row0 + ty * 4 + i;
        const int nn0 = col0 + tx * 4;
        size_t idx;
        if (FLAGS & F_SPLIT) {
            const int bb = mm >> 12;
            const int ss = mm & 4095;
            const int hh = nn0 >> 6;
            const int dk = nn0 & 63;
            idx = (((size_t)(bb * CH + hh)) * CS + ss) * CDK + dk;
        } else {
            idx = (size_t)mm * N + nn0;
        }
        u16x4 ov;
#pragma unroll
        for (int j = 0; j < 4; j++) {
            float val = acc[i][j];
            if (FLAGS & F_BIAS) val += bf2f(bias[nn0 + j]);
            if (FLAGS & F_RELU) val = fmaxf(val, 0.f);
            ov[j] = f2bf(val);
        }
        *(u16x4*)(C + idx) = ov;
    }
}

// ---------------------------------------------------------------------------
// MFMA flash attention.
// grid (S/64, B*H), 256 threads = 4 waves. Wave w owns queries [w*16, w*16+16).
// Per 64-key tile: stage K (row-major, pad 8) + V^T (pad 8, u32 pair-packed
// writes) in LDS; QK^T = 8 MFMA -> online softmax in regs (C-layout row
// stats, shuffle-reduce xor 1/2/4/8) -> P via per-wave LDS buffer (A-layout
// re-read, no barrier) -> PV = 8 MFMA into O frags.
// Layouts (guide §3, m89/m91/m120 verified):
//   A[m=lane&15][k=quad*8+j], B[k=quad*8+j][n=lane&15],
//   C/D: col=lane&15, row=quad*4+reg.
// ---------------------------------------------------------------------------
#define KP 72  // padded row length (u16) for K/Vt/P LDS tiles

__global__ __launch_bounds__(256, 4) void mfma_attn(
    const u16* __restrict__ Qb, const u16* __restrict__ Kb,
    const u16* __restrict__ Vb, const int* __restrict__ mask,
    u16* __restrict__ ctx)
{
    __shared__ u16 Ksh[64 * KP];
    __shared__ u16 Vts[64 * KP];
    __shared__ u16 Psh[4][16 * KP];
    __shared__ int msk[64];

    const int tid = threadIdx.x;
    const int lane = tid & 63;
    const int wave = tid >> 6;
    const int lrow = lane & 15;
    const int quad = lane >> 4;

    const int bh = blockIdx.y;
    const int b = bh / CH;
    const int h = bh % CH;
    const int q0 = blockIdx.x * 64;

    // Q fragments (held all kernel): wave's query row lrow, k-chunks 0/1
    const u16* qbase = Qb + (((size_t)bh * CS) + q0 + wave * 16 + lrow) * CDK + quad * 8;
    bf16x8 aq0 = *(const bf16x8*)(qbase);
    bf16x8 aq1 = *(const bf16x8*)(qbase + 32);

    f32x4 o[4];
#pragma unroll
    for (int ft = 0; ft < 4; ft++) o[ft] = f32x4{0.f, 0.f, 0.f, 0.f};
    float m_i[4], l_i[4];
#pragma unroll
    for (int r = 0; r < 4; r++) { m_i[r] = -1e30f; l_i[r] = 0.f; }

    u16* Pw = &Psh[wave][0];

    for (int t = 0; t < CS; t += 64) {
        const u16* kp = Kb + ((size_t)bh * CS + t) * CDK;
        const u16* vp = Vb + ((size_t)bh * CS + t) * CDK;
        __syncthreads();
        // ---- stage K tile: 512 u16x8 chunks, 2 per thread (b128 LDS writes)
#pragma unroll
        for (int i = 0; i < 2; i++) {
            int c = tid * 2 + i;
            int row = c >> 3, col = (c & 7) * 8;
            u16x8 kv = *(const u16x8*)(kp + row * CDK + col);
            *(u16x8*)&Ksh[row * KP + col] = kv;
        }
        // ---- stage V transposed: thread = (key-pair a, dk-chunk c); u32 writes
        {
            int a = tid & 31;     // key pair
            int c = tid >> 5;     // dk chunk
            const u16* v0 = vp + (2 * a) * CDK + c * 8;
            u16x8 r0 = *(const u16x8*)v0;
            u16x8 r1 = *(const u16x8*)(v0 + CDK);
#pragma unroll
            for (int j = 0; j < 8; j++) {
                unsigned int pk = (unsigned int)r0[j] | ((unsigned int)r1[j] << 16);
                *(unsigned int*)&Vts[(c * 8 + j) * KP + 2 * a] = pk;
            }
        }
        if (tid < 64) msk[tid] = mask[b * CS + t + tid];
        __syncthreads();

        // ---- scores: 16x64 per wave = 4 col-tiles x 2 MFMA
        f32x4 sc[4];
#pragma unroll
        for (int ft = 0; ft < 4; ft++) {
            const u16* kr = &Ksh[(ft * 16 + lrow) * KP + quad * 8];
            bf16x8 bk0 = *(const bf16x8*)(kr);
            bf16x8 bk1 = *(const bf16x8*)(kr + 32);
            f32x4 c = f32x4{0.f, 0.f, 0.f, 0.f};
            c = __builtin_amdgcn_mfma_f32_16x16x32_bf16(aq0, bk0, c, 0, 0, 0);
            c = __builtin_amdgcn_mfma_f32_16x16x32_bf16(aq1, bk1, c, 0, 0, 0);
            sc[ft] = c;
        }
        // scale + mask
#pragma unroll
        for (int ft = 0; ft < 4; ft++) {
            int mk = msk[ft * 16 + lrow];
#pragma unroll
            for (int r = 0; r < 4; r++) {
                float s = sc[ft][r] * 0.125f;
                sc[ft][r] = (mk == 0) ? -1e9f : s;
            }
        }
        // ---- online softmax (rows live in 16-lane groups; xor 1/2/4/8)
        float tm[4], rs[4], alpha[4];
#pragma unroll
        for (int r = 0; r < 4; r++)
            tm[r] = fmaxf(fmaxf(sc[0][r], sc[1][r]), fmaxf(sc[2][r], sc[3][r]));
#pragma unroll
        for (int x = 1; x < 16; x <<= 1)
#pragma unroll
            for (int r = 0; r < 4; r++)
                tm[r] = fmaxf(tm[r], __shfl_xor(tm[r], x, 64));
#pragma unroll
        for (int r = 0; r < 4; r++) {
            float mn = fmaxf(m_i[r], tm[r]);
            alpha[r] = __expf(m_i[r] - mn);
            m_i[r] = mn;
            rs[r] = 0.f;
        }
#pragma unroll
        for (int ft = 0; ft < 4; ft++)
#pragma unroll
            for (int r = 0; r < 4; r++) {
                float p = __expf(sc[ft][r] - m_i[r]);
                sc[ft][r] = p;
                rs[r] += p;
            }
#pragma unroll
        for (int x = 1; x < 16; x <<= 1)
#pragma unroll
            for (int r = 0; r < 4; r++)
                rs[r] += __shfl_xor(rs[r], x, 64);
#pragma unroll
        for (int r = 0; r < 4; r++) l_i[r] = l_i[r] * alpha[r] + rs[r];
        // rescale O accumulators
#pragma unroll
        for (int ft = 0; ft < 4; ft++)
#pragma unroll
            for (int r = 0; r < 4; r++) o[ft][r] *= alpha[r];
        // ---- P: C-layout -> per-wave LDS -> A-layout (no barrier: same wave)
#pragma unroll
        for (int ft = 0; ft < 4; ft++)
#pragma unroll
            for (int r = 0; r < 4; r++)
                Pw[(quad * 4 + r) * KP + ft * 16 + lrow] = f2bf(sc[ft][r]);

        bf16x8 ap0 = *(const bf16x8*)&Pw[lrow * KP + quad * 8];
        bf16x8 ap1 = *(const bf16x8*)&Pw[lrow * KP + quad * 8 + 32];
#pragma unroll
        for (int ft = 0; ft < 4; ft++) {
            const u16* vr = &Vts[(ft * 16 + lrow) * KP + quad * 8];
            bf16x8 bv0 = *(const bf16x8*)(vr);
            bf16x8 bv1 = *(const bf16x8*)(vr + 32);
            f32x4 c = o[ft];
            c = __builtin_amdgcn_mfma_f32_16x16x32_bf16(ap0, bv0, c, 0, 0, 0);
            c = __builtin_amdgcn_mfma_f32_16x16x32_bf16(ap1, bv1, c, 0, 0, 0);
            o[ft] = c;
        }
    }

    // ---- epilogue: O/l -> per-wave LDS (C-layout scatter) -> coalesced store
    float inv[4];
#pragma unroll
    for (int r = 0; r < 4; r++) inv[r] = 1.f / l_i[r];
#pragma unroll
    for (int ft = 0; ft < 4; ft++)
#pragma unroll
        for (int r = 0; r < 4; r++)
            Pw[(quad * 4 + r) * KP + ft * 16 + lrow] = f2bf(o[ft][r] * inv[r]);

#pragma unroll
    for (int i = 0; i < 2; i++) {
        int c = lane + i * 64;
        int row = c >> 3, off = (c & 7) * 8;
        u16x8 tv = *(const u16x8*)&Pw[row * KP + off];
        *(u16x8*)(ctx + (((size_t)b * CS) + q0 + wave * 16 + row) * CD + h * CDK + off) = tv;
    }
}

// ---------------------------------------------------------------------------
// Residual + LayerNorm (unchanged).
// ---------------------------------------------------------------------------
__global__ __launch_bounds__(256) void ln_kernel(
    const u16* __restrict__ xa, const u16* __restrict__ xb,
    const u16* __restrict__ g, const u16* __restrict__ be,
    u16* __restrict__ outb, float* __restrict__ outf,
    const int* __restrict__ flag)
{
    const int lane = threadIdx.x & 63;
    const int wave = threadIdx.x >> 6;
    const size_t row = (size_t)blockIdx.x * 4 + wave;
    const int c0 = lane * 8;

    u16x8 av = *(const u16x8*)(xa + row * CD + c0);
    u16x8 bv = *(const u16x8*)(xb + row * CD + c0);

    float v[8];
    float s1 = 0.f, s2 = 0.f;
#pragma unroll
    for (int e = 0; e < 8; e++) {
        v[e] = bf2f(av[e]) + bf2f(bv[e]);
        s1 += v[e];
        s2 += v[e] * v[e];
    }
#pragma unroll
    for (int off = 32; off > 0; off >>= 1) {
        s1 += __shfl_xor(s1, off, 64);
        s2 += __shfl_xor(s2, off, 64);
    }
    const float mu = s1 * (1.f / CD);
    const float var = fmaxf(s2 * (1.f / CD) - mu * mu, 0.f);
    const float r = rsqrtf(var + 1e-5f);

    u16x8 gv = *(const u16x8*)(g + c0);
    u16x8 ev = *(const u16x8*)(be + c0);
    float res[8];
#pragma unroll
    for (int e = 0; e < 8; e++)
        res[e] = (v[e] - mu) * r * bf2f(gv[e]) + bf2f(ev[e]);

    const int flg = *flag;
    const bool f32out = (outf != nullptr) && (flg == 0);
    if (f32out) {
        float4 o0 = make_float4(res[0], res[1], res[2], res[3]);
        float4 o1 = make_float4(res[4], res[5], res[6], res[7]);
        *(float4*)(outf + row * CD + c0) = o0;
        *(float4*)(outf + row * CD + c0 + 4) = o1;
    } else {
        u16x8 ov;
#pragma unroll
        for (int e = 0; e < 8; e++) ov[e] = f2bf(res[e]);
        *(u16x8*)(outb + row * CD + c0) = ov;
    }
}

// ---------------------------------------------------------------------------

extern "C" void kernel_launch(void* const* d_in, const int* in_sizes, int n_in,
                              void* d_out, int out_size, void* d_ws, size_t ws_size,
                              hipStream_t stream)
{
    const void* x_raw   = d_in[0];
    const int*  mask    = (const int*)d_in[1];
    const void* wq_raw  = d_in[2];
    const void* wk_raw  = d_in[3];
    const void* wv_raw  = d_in[4];
    const void* wo_raw  = d_in[5];
    const void* w1_raw  = d_in[6];
    const void* b1_raw  = d_in[7];
    const void* w2_raw  = d_in[8];
    const void* b2_raw  = d_in[9];
    const void* g1_raw  = d_in[10];
    const void* be1_raw = d_in[11];
    const void* g2_raw  = d_in[12];
    const void* be2_raw = d_in[13];

    const size_t NX = (size_t)CB * CS * CD;      // 4,194,304
    const size_t WSZ = (size_t)CD * CD;          // 262,144
    const size_t W1SZ = (size_t)CD * CDFF;       // 1,048,576

    u16* ws = (u16*)d_ws;
    int* flag = (int*)d_ws;
    u16* base = ws + 1024;
    u16* xc  = base;
    u16* q   = base + 1 * NX;
    u16* k   = base + 2 * NX;
    u16* v   = base + 3 * NX;
    u16* ctx = base + 4 * NX;
    u16* att = base + 5 * NX;
    u16* x1  = base + 6 * NX;
    u16* ffo = base + 7 * NX;
    u16* ffh = base + 8 * NX;          // 4*NX
    u16* wt  = base + 12 * NX;
    u16* wqc = wt;
    u16* wkc = wqc + WSZ;
    u16* wvc = wkc + WSZ;
    u16* woc = wvc + WSZ;
    u16* w1c = woc + WSZ;
    u16* w2c = w1c + W1SZ;
    u16* b1c = w2c + W1SZ;
    u16* b2c = b1c + CDFF;
    u16* g1c = b2c + CD;
    u16* be1c = g1c + CD;
    u16* g2c = be1c + CD;
    u16* be2c = g2c + CD;
    u16* wend = be2c + CD;

    const size_t need = (size_t)(wend - ws) * sizeof(u16);
    if (ws_size < need) return;

    detect_dtype<<<1, 256, 0, stream>>>((const unsigned int*)x_raw, flag);

    auto conv = [&](const void* src, u16* dst, int n) {
        int blocks = (n + 256 * 8 - 1) / (256 * 8);
        if (blocks > 1024) blocks = 1024;
        if (blocks < 1) blocks = 1;
        convert_bf16<<<blocks, 256, 0, stream>>>(src, dst, n, flag);
    };
    conv(x_raw, xc, (int)NX);
    conv(wq_raw, wqc, (int)WSZ);
    conv(wk_raw, wkc, (int)WSZ);
    conv(wv_raw, wvc, (int)WSZ);
    conv(wo_raw, woc, (int)WSZ);
    conv(w1_raw, w1c, (int)W1SZ);
    conv(w2_raw, w2c, (int)W1SZ);
    conv(b1_raw, b1c, CDFF);
    conv(b2_raw, b2c, CD);
    conv(g1_raw, g1c, CD);
    conv(be1_raw, be1c, CD);
    conv(g2_raw, g2c, CD);
    conv(be2_raw, be2c, CD);

    const int M = CB * CS;  // 8192

    dim3 gProj(CD / 64, M / 64);
    gemm_bf16<F_SPLIT><<<gProj, 256, 0, stream>>>(xc, wqc, nullptr, q, M, CD, CD);
    gemm_bf16<F_SPLIT><<<gProj, 256, 0, stream>>>(xc, wkc, nullptr, k, M, CD, CD);
    gemm_bf16<F_SPLIT><<<gProj, 256, 0, stream>>>(xc, wvc, nullptr, v, M, CD, CD);

    mfma_attn<<<dim3(CS / 64, CB * CH), 256, 0, stream>>>(q, k, v, mask, ctx);

    gemm_bf16<0><<<gProj, 256, 0, stream>>>(ctx, woc, nullptr, att, M, CD, CD);

    ln_kernel<<<dim3(M / 4), 256, 0, stream>>>(xc, att, g1c, be1c, x1, nullptr, flag);

    gemm_bf16<F_BIAS | F_RELU><<<dim3(CDFF / 64, M / 64), 256, 0, stream>>>(
        x1, w1c, b1c, ffh, M, CDFF, CD);
    gemm_bf16<F_BIAS><<<gProj, 256, 0, stream>>>(ffh, w2c, b2c, ffo, M, CD, CDFF);

    ln_kernel<<<dim3(M / 4), 256, 0, stream>>>(x1, ffo, g2c, be2c,
                                               (u16*)d_out, (float*)d_out, flag);
}

// Round 5
// 487.460 us; speedup vs baseline: 14.3752x; 2.0737x over previous
//
#include <hip/hip_runtime.h>
#include <hip/hip_bf16.h>

// ---------------------------------------------------------------------------
// EncoderLayer (round 5): MFMA GEMMs (128x128 tile, 16x16x32 bf16, B^T
// operand, m93-style VGPR staging) + MFMA flash attention (round 4).
// Weights transposed during fp32->bf16 convert; QKV fused into one GEMM.
// B=2, S=4096, D=512, H=8, DK=64, DFF=2048.
// ---------------------------------------------------------------------------

typedef unsigned short u16;
typedef __attribute__((ext_vector_type(4))) u16 u16x4;
typedef __attribute__((ext_vector_type(8))) u16 u16x8;
typedef __attribute__((ext_vector_type(4))) float f32x4;
typedef __attribute__((ext_vector_type(8))) short bf16x8;  // MFMA A/B frag

#define CB 2
#define CS 4096
#define CD 512
#define CH 8
#define CDK 64
#define CDFF 2048
#define NXC ((size_t)CB * CS * CD)

__device__ __forceinline__ float bf2f(u16 u) {
    union { unsigned int i; float f; } c;
    c.i = ((unsigned int)u) << 16;
    return c.f;
}

__device__ __forceinline__ u16 f2bf(float f) {
    unsigned int x = __float_as_uint(f);
    unsigned int r = (x + 0x7fffu + ((x >> 16) & 1u)) >> 16;  // RNE
    return (u16)r;
}

// ---------------------------------------------------------------------------
// Dtype detection (bf16-packed vs fp32). flag=1 -> bf16.
// ---------------------------------------------------------------------------
__global__ void detect_dtype(const unsigned int* __restrict__ xw, int* __restrict__ flag) {
    __shared__ int red[256];
    int sane = 0;
    for (int i = threadIdx.x; i < 2048; i += 256) {
        unsigned int w = xw[i];
        unsigned int lo = w & 0xFFFFu;
        unsigned int e = (lo >> 7) & 0xFFu;
        if (lo == 0u || lo == 0x8000u || (e >= 96u && e <= 159u)) sane++;
    }
    red[threadIdx.x] = sane;
    __syncthreads();
    for (int s = 128; s > 0; s >>= 1) {
        if ((int)threadIdx.x < s) red[threadIdx.x] += red[threadIdx.x + s];
        __syncthreads();
    }
    if (threadIdx.x == 0) *flag = (red[0] >= 1843) ? 1 : 0;
}

__global__ __launch_bounds__(256) void convert_bf16(
    const void* __restrict__ src, u16* __restrict__ dst, int n,
    const int* __restrict__ flag)
{
    const bool isbf = (*flag != 0);
    int i = blockIdx.x * 256 + threadIdx.x;
    const int stride = gridDim.x * 256;
    if (isbf) {
        const u16* s = (const u16*)src;
        for (; i < n; i += stride) dst[i] = s[i];
    } else {
        const float* s = (const float*)src;
        for (; i < n; i += stride) dst[i] = f2bf(s[i]);
    }
}

struct SmallConv {
    const void* src[6];
    u16* dst[6];
    int n[6];
};

__global__ __launch_bounds__(256) void convert_small(SmallConv sc, const int* __restrict__ flag) {
    const bool isbf = (*flag != 0);
    for (int t = 0; t < 6; t++) {
        for (int i = threadIdx.x; i < sc.n[t]; i += 256) {
            if (isbf) sc.dst[t][i] = ((const u16*)sc.src[t])[i];
            else sc.dst[t][i] = f2bf(((const float*)sc.src[t])[i]);
        }
    }
}

// ---------------------------------------------------------------------------
// Transposed convert: dst[c*R + r] = cvt(src[r*Cc + c]).  32x32 LDS tiles.
// grid (Cc/32, R/32), 256 threads.
// ---------------------------------------------------------------------------
__global__ __launch_bounds__(256) void transpose_cvt(
    const void* __restrict__ src, u16* __restrict__ dst,
    int R, int Cc, const int* __restrict__ flag)
{
    __shared__ float t[32][33];
    const bool isbf = (*flag != 0);
    const int r0 = blockIdx.y * 32;
    const int c0 = blockIdx.x * 32;
    const int col = threadIdx.x & 31;
    const int row = threadIdx.x >> 5;  // 0..7
#pragma unroll
    for (int it = 0; it < 4; it++) {
        int rr = row + it * 8;
        float v;
        if (isbf) v = bf2f(((const u16*)src)[(size_t)(r0 + rr) * Cc + c0 + col]);
        else v = ((const float*)src)[(size_t)(r0 + rr) * Cc + c0 + col];
        t[rr][col] = v;
    }
    __syncthreads();
#pragma unroll
    for (int it = 0; it < 4; it++) {
        int rr = row + it * 8;
        dst[(size_t)(c0 + rr) * R + r0 + col] = f2bf(t[col][rr]);
    }
}

// ---------------------------------------------------------------------------
// MFMA GEMM: C[M,N] = A[M,K] * Bt[N,K]^T.  BM=BN=128, BK=32, 256 thr = 4
// waves (2x2 of 64x64), each wave 4x4 frags of 16x16x32 bf16 MFMA.
// LDS tiles stride-padded to 40 u16 (80 B) to spread banks; b128 aligned.
// FLAGS: 1=QKV head-split output (C base = q, +proj*NXC), 2=bias, 4=relu.
// ---------------------------------------------------------------------------
#define F_SPLIT 1
#define F_BIAS  2
#define F_RELU  4
#define LSTR 40

template <int FLAGS>
__global__ __launch_bounds__(256, 2) void gemm_mfma(
    const u16* __restrict__ A, const u16* __restrict__ Bt,
    const u16* __restrict__ bias, u16* __restrict__ C,
    int M, int N, int K)
{
    __shared__ u16 Asb[128 * LSTR];
    __shared__ u16 Bsb[128 * LSTR];

    const int tid = threadIdx.x;
    const int lane = tid & 63;
    const int wave = tid >> 6;
    const int lrow = lane & 15;
    const int quad = lane >> 4;
    const int wm = wave & 1;
    const int wn = wave >> 1;
    const int m0 = blockIdx.y * 128;
    const int n0 = blockIdx.x * 128;

    // staging map: thread covers 32 consecutive bf16 of one tile row
    const int srow = tid >> 1;          // 0..127
    const int skc = (tid & 1) * 16;     // element offset 0 or 16

    f32x4 acc[4][4];
#pragma unroll
    for (int i = 0; i < 4; i++)
#pragma unroll
        for (int j = 0; j < 4; j++) acc[i][j] = f32x4{0.f, 0.f, 0.f, 0.f};

    const u16* Ap = A + (size_t)(m0 + srow) * K + skc;
    const u16* Bp = Bt + (size_t)(n0 + srow) * K + skc;

    for (int k0 = 0; k0 < K; k0 += 32) {
        u16x8 a0 = *(const u16x8*)(Ap + k0);
        u16x8 a1 = *(const u16x8*)(Ap + k0 + 8);
        u16x8 b0 = *(const u16x8*)(Bp + k0);
        u16x8 b1 = *(const u16x8*)(Bp + k0 + 8);
        __syncthreads();
        *(u16x8*)&Asb[srow * LSTR + skc] = a0;
        *(u16x8*)&Asb[srow * LSTR + skc + 8] = a1;
        *(u16x8*)&Bsb[srow * LSTR + skc] = b0;
        *(u16x8*)&Bsb[srow * LSTR + skc + 8] = b1;
        __syncthreads();

        bf16x8 af[4], bfr[4];
#pragma unroll
        for (int i = 0; i < 4; i++)
            af[i] = *(const bf16x8*)&Asb[(wm * 64 + i * 16 + lrow) * LSTR + quad * 8];
#pragma unroll
        for (int j = 0; j < 4; j++)
            bfr[j] = *(const bf16x8*)&Bsb[(wn * 64 + j * 16 + lrow) * LSTR + quad * 8];
#pragma unroll
        for (int i = 0; i < 4; i++)
#pragma unroll
            for (int j = 0; j < 4; j++)
                acc[i][j] = __builtin_amdgcn_mfma_f32_16x16x32_bf16(
                    af[i], bfr[j], acc[i][j], 0, 0, 0);
    }

    // epilogue: C/D layout col(n)=lane&15, row(m)=quad*4+r
    const int mbase = m0 + wm * 64;
    const int nbase = n0 + wn * 64;
#pragma unroll
    for (int i = 0; i < 4; i++) {
#pragma unroll
        for (int r = 0; r < 4; r++) {
            const int m = mbase + i * 16 + quad * 4 + r;
#pragma unroll
            for (int j = 0; j < 4; j++) {
                const int n = nbase + j * 16 + lrow;
                float val = acc[i][j][r];
                if (FLAGS & F_BIAS) val += bf2f(bias[n]);
                if (FLAGS & F_RELU) val = fmaxf(val, 0.f);
                if (FLAGS & F_SPLIT) {
                    const int proj = n >> 9;       // 0=q,1=k,2=v
                    const int d = n & 511;
                    const int h = d >> 6;
                    const int dk = d & 63;
                    const int bb = m >> 12;
                    const int ss = m & 4095;
                    C[proj * NXC + (((size_t)(bb * CH + h)) * CS + ss) * CDK + dk] = f2bf(val);
                } else {
                    C[(size_t)m * N + n] = f2bf(val);
                }
            }
        }
    }
}

// ---------------------------------------------------------------------------
// MFMA flash attention (round 4, unchanged).
// ---------------------------------------------------------------------------
#define KP 72

__global__ __launch_bounds__(256, 4) void mfma_attn(
    const u16* __restrict__ Qb, const u16* __restrict__ Kb,
    const u16* __restrict__ Vb, const int* __restrict__ mask,
    u16* __restrict__ ctx)
{
    __shared__ u16 Ksh[64 * KP];
    __shared__ u16 Vts[64 * KP];
    __shared__ u16 Psh[4][16 * KP];
    __shared__ int msk[64];

    const int tid = threadIdx.x;
    const int lane = tid & 63;
    const int wave = tid >> 6;
    const int lrow = lane & 15;
    const int quad = lane >> 4;

    const int bh = blockIdx.y;
    const int b = bh / CH;
    const int h = bh % CH;
    const int q0 = blockIdx.x * 64;

    const u16* qbase = Qb + (((size_t)bh * CS) + q0 + wave * 16 + lrow) * CDK + quad * 8;
    bf16x8 aq0 = *(const bf16x8*)(qbase);
    bf16x8 aq1 = *(const bf16x8*)(qbase + 32);

    f32x4 o[4];
#pragma unroll
    for (int ft = 0; ft < 4; ft++) o[ft] = f32x4{0.f, 0.f, 0.f, 0.f};
    float m_i[4], l_i[4];
#pragma unroll
    for (int r = 0; r < 4; r++) { m_i[r] = -1e30f; l_i[r] = 0.f; }

    u16* Pw = &Psh[wave][0];

    for (int t = 0; t < CS; t += 64) {
        const u16* kp = Kb + ((size_t)bh * CS + t) * CDK;
        const u16* vp = Vb + ((size_t)bh * CS + t) * CDK;
        __syncthreads();
#pragma unroll
        for (int i = 0; i < 2; i++) {
            int c = tid * 2 + i;
            int row = c >> 3, col = (c & 7) * 8;
            u16x8 kv = *(const u16x8*)(kp + row * CDK + col);
            *(u16x8*)&Ksh[row * KP + col] = kv;
        }
        {
            int a = tid & 31;
            int c = tid >> 5;
            const u16* v0 = vp + (2 * a) * CDK + c * 8;
            u16x8 r0 = *(const u16x8*)v0;
            u16x8 r1 = *(const u16x8*)(v0 + CDK);
#pragma unroll
            for (int j = 0; j < 8; j++) {
                unsigned int pk = (unsigned int)r0[j] | ((unsigned int)r1[j] << 16);
                *(unsigned int*)&Vts[(c * 8 + j) * KP + 2 * a] = pk;
            }
        }
        if (tid < 64) msk[tid] = mask[b * CS + t + tid];
        __syncthreads();

        f32x4 sc[4];
#pragma unroll
        for (int ft = 0; ft < 4; ft++) {
            const u16* kr = &Ksh[(ft * 16 + lrow) * KP + quad * 8];
            bf16x8 bk0 = *(const bf16x8*)(kr);
            bf16x8 bk1 = *(const bf16x8*)(kr + 32);
            f32x4 c = f32x4{0.f, 0.f, 0.f, 0.f};
            c = __builtin_amdgcn_mfma_f32_16x16x32_bf16(aq0, bk0, c, 0, 0, 0);
            c = __builtin_amdgcn_mfma_f32_16x16x32_bf16(aq1, bk1, c, 0, 0, 0);
            sc[ft] = c;
        }
#pragma unroll
        for (int ft = 0; ft < 4; ft++) {
            int mk = msk[ft * 16 + lrow];
#pragma unroll
            for (int r = 0; r < 4; r++) {
                float s = sc[ft][r] * 0.125f;
                sc[ft][r] = (mk == 0) ? -1e9f : s;
            }
        }
        float tm[4], rs[4], alpha[4];
#pragma unroll
        for (int r = 0; r < 4; r++)
            tm[r] = fmaxf(fmaxf(sc[0][r], sc[1][r]), fmaxf(sc[2][r], sc[3][r]));
#pragma unroll
        for (int x = 1; x < 16; x <<= 1)
#pragma unroll
            for (int r = 0; r < 4; r++)
                tm[r] = fmaxf(tm[r], __shfl_xor(tm[r], x, 64));
#pragma unroll
        for (int r = 0; r < 4; r++) {
            float mn = fmaxf(m_i[r], tm[r]);
            alpha[r] = __expf(m_i[r] - mn);
            m_i[r] = mn;
            rs[r] = 0.f;
        }
#pragma unroll
        for (int ft = 0; ft < 4; ft++)
#pragma unroll
            for (int r = 0; r < 4; r++) {
                float p = __expf(sc[ft][r] - m_i[r]);
                sc[ft][r] = p;
                rs[r] += p;
            }
#pragma unroll
        for (int x = 1; x < 16; x <<= 1)
#pragma unroll
            for (int r = 0; r < 4; r++)
                rs[r] += __shfl_xor(rs[r], x, 64);
#pragma unroll
        for (int r = 0; r < 4; r++) l_i[r] = l_i[r] * alpha[r] + rs[r];
#pragma unroll
        for (int ft = 0; ft < 4; ft++)
#pragma unroll
            for (int r = 0; r < 4; r++) o[ft][r] *= alpha[r];
#pragma unroll
        for (int ft = 0; ft < 4; ft++)
#pragma unroll
            for (int r = 0; r < 4; r++)
                Pw[(quad * 4 + r) * KP + ft * 16 + lrow] = f2bf(sc[ft][r]);

        bf16x8 ap0 = *(const bf16x8*)&Pw[lrow * KP + quad * 8];
        bf16x8 ap1 = *(const bf16x8*)&Pw[lrow * KP + quad * 8 + 32];
#pragma unroll
        for (int ft = 0; ft < 4; ft++) {
            const u16* vr = &Vts[(ft * 16 + lrow) * KP + quad * 8];
            bf16x8 bv0 = *(const bf16x8*)(vr);
            bf16x8 bv1 = *(const bf16x8*)(vr + 32);
            f32x4 c = o[ft];
            c = __builtin_amdgcn_mfma_f32_16x16x32_bf16(ap0, bv0, c, 0, 0, 0);
            c = __builtin_amdgcn_mfma_f32_16x16x32_bf16(ap1, bv1, c, 0, 0, 0);
            o[ft] = c;
        }
    }

    float inv[4];
#pragma unroll
    for (int r = 0; r < 4; r++) inv[r] = 1.f / l_i[r];
#pragma unroll
    for (int ft = 0; ft < 4; ft++)
#pragma unroll
        for (int r = 0; r < 4; r++)
            Pw[(quad * 4 + r) * KP + ft * 16 + lrow] = f2bf(o[ft][r] * inv[r]);

#pragma unroll
    for (int i = 0; i < 2; i++) {
        int c = lane + i * 64;
        int row = c >> 3, off = (c & 7) * 8;
        u16x8 tv = *(const u16x8*)&Pw[row * KP + off];
        *(u16x8*)(ctx + (((size_t)b * CS) + q0 + wave * 16 + row) * CD + h * CDK + off) = tv;
    }
}

// ---------------------------------------------------------------------------
// Residual + LayerNorm (unchanged).
// ---------------------------------------------------------------------------
__global__ __launch_bounds__(256) void ln_kernel(
    const u16* __restrict__ xa, const u16* __restrict__ xb,
    const u16* __restrict__ g, const u16* __restrict__ be,
    u16* __restrict__ outb, float* __restrict__ outf,
    const int* __restrict__ flag)
{
    const int lane = threadIdx.x & 63;
    const int wave = threadIdx.x >> 6;
    const size_t row = (size_t)blockIdx.x * 4 + wave;
    const int c0 = lane * 8;

    u16x8 av = *(const u16x8*)(xa + row * CD + c0);
    u16x8 bv = *(const u16x8*)(xb + row * CD + c0);

    float v[8];
    float s1 = 0.f, s2 = 0.f;
#pragma unroll
    for (int e = 0; e < 8; e++) {
        v[e] = bf2f(av[e]) + bf2f(bv[e]);
        s1 += v[e];
        s2 += v[e] * v[e];
    }
#pragma unroll
    for (int off = 32; off > 0; off >>= 1) {
        s1 += __shfl_xor(s1, off, 64);
        s2 += __shfl_xor(s2, off, 64);
    }
    const float mu = s1 * (1.f / CD);
    const float var = fmaxf(s2 * (1.f / CD) - mu * mu, 0.f);
    const float r = rsqrtf(var + 1e-5f);

    u16x8 gv = *(const u16x8*)(g + c0);
    u16x8 ev = *(const u16x8*)(be + c0);
    float res[8];
#pragma unroll
    for (int e = 0; e < 8; e++)
        res[e] = (v[e] - mu) * r * bf2f(gv[e]) + bf2f(ev[e]);

    const int flg = *flag;
    const bool f32out = (outf != nullptr) && (flg == 0);
    if (f32out) {
        float4 o0 = make_float4(res[0], res[1], res[2], res[3]);
        float4 o1 = make_float4(res[4], res[5], res[6], res[7]);
        *(float4*)(outf + row * CD + c0) = o0;
        *(float4*)(outf + row * CD + c0 + 4) = o1;
    } else {
        u16x8 ov;
#pragma unroll
        for (int e = 0; e < 8; e++) ov[e] = f2bf(res[e]);
        *(u16x8*)(outb + row * CD + c0) = ov;
    }
}

// ---------------------------------------------------------------------------

extern "C" void kernel_launch(void* const* d_in, const int* in_sizes, int n_in,
                              void* d_out, int out_size, void* d_ws, size_t ws_size,
                              hipStream_t stream)
{
    const void* x_raw   = d_in[0];
    const int*  mask    = (const int*)d_in[1];
    const void* wq_raw  = d_in[2];
    const void* wk_raw  = d_in[3];
    const void* wv_raw  = d_in[4];
    const void* wo_raw  = d_in[5];
    const void* w1_raw  = d_in[6];
    const void* b1_raw  = d_in[7];
    const void* w2_raw  = d_in[8];
    const void* b2_raw  = d_in[9];
    const void* g1_raw  = d_in[10];
    const void* be1_raw = d_in[11];
    const void* g2_raw  = d_in[12];
    const void* be2_raw = d_in[13];

    const size_t NX = NXC;                       // 4,194,304
    const size_t WSZ = (size_t)CD * CD;          // 262,144
    const size_t W1SZ = (size_t)CD * CDFF;       // 1,048,576

    u16* ws = (u16*)d_ws;
    int* flag = (int*)d_ws;
    u16* base = ws + 1024;
    u16* xc  = base;
    u16* q   = base + 1 * NX;
    u16* k   = base + 2 * NX;
    u16* v   = base + 3 * NX;
    u16* ctx = base + 4 * NX;
    u16* att = base + 5 * NX;
    u16* x1  = base + 6 * NX;
    u16* ffo = base + 7 * NX;
    u16* ffh = base + 8 * NX;          // 4*NX
    u16* wt  = base + 12 * NX;
    u16* wqkvT = wt;                   // [1536][512]
    u16* woT = wqkvT + 3 * WSZ;        // [512][512]
    u16* w1T = woT + WSZ;              // [2048][512]
    u16* w2T = w1T + W1SZ;             // [512][2048]
    u16* b1c = w2T + W1SZ;
    u16* b2c = b1c + CDFF;
    u16* g1c = b2c + CD;
    u16* be1c = g1c + CD;
    u16* g2c = be1c + CD;
    u16* be2c = g2c + CD;
    u16* wend = be2c + CD;

    const size_t need = (size_t)(wend - ws) * sizeof(u16);
    if (ws_size < need) return;

    detect_dtype<<<1, 256, 0, stream>>>((const unsigned int*)x_raw, flag);

    convert_bf16<<<1024, 256, 0, stream>>>(x_raw, xc, (int)NX, flag);

    // weight transposes: dst[n][k] = src[k][n]
    transpose_cvt<<<dim3(CD / 32, CD / 32), 256, 0, stream>>>(wq_raw, wqkvT, CD, CD, flag);
    transpose_cvt<<<dim3(CD / 32, CD / 32), 256, 0, stream>>>(wk_raw, wqkvT + WSZ, CD, CD, flag);
    transpose_cvt<<<dim3(CD / 32, CD / 32), 256, 0, stream>>>(wv_raw, wqkvT + 2 * WSZ, CD, CD, flag);
    transpose_cvt<<<dim3(CD / 32, CD / 32), 256, 0, stream>>>(wo_raw, woT, CD, CD, flag);
    transpose_cvt<<<dim3(CDFF / 32, CD / 32), 256, 0, stream>>>(w1_raw, w1T, CD, CDFF, flag);
    transpose_cvt<<<dim3(CD / 32, CDFF / 32), 256, 0, stream>>>(w2_raw, w2T, CDFF, CD, flag);

    SmallConv sc;
    sc.src[0] = b1_raw;  sc.dst[0] = b1c;  sc.n[0] = CDFF;
    sc.src[1] = b2_raw;  sc.dst[1] = b2c;  sc.n[1] = CD;
    sc.src[2] = g1_raw;  sc.dst[2] = g1c;  sc.n[2] = CD;
    sc.src[3] = be1_raw; sc.dst[3] = be1c; sc.n[3] = CD;
    sc.src[4] = g2_raw;  sc.dst[4] = g2c;  sc.n[4] = CD;
    sc.src[5] = be2_raw; sc.dst[5] = be2c; sc.n[5] = CD;
    convert_small<<<1, 256, 0, stream>>>(sc, flag);

    const int M = CB * CS;  // 8192

    // fused QKV: [8192 x 1536] = xc[8192x512] * wqkvT[1536x512]^T, split out
    gemm_mfma<F_SPLIT><<<dim3(1536 / 128, M / 128), 256, 0, stream>>>(
        xc, wqkvT, nullptr, q, M, 1536, CD);

    mfma_attn<<<dim3(CS / 64, CB * CH), 256, 0, stream>>>(q, k, v, mask, ctx);

    gemm_mfma<0><<<dim3(CD / 128, M / 128), 256, 0, stream>>>(
        ctx, woT, nullptr, att, M, CD, CD);

    ln_kernel<<<dim3(M / 4), 256, 0, stream>>>(xc, att, g1c, be1c, x1, nullptr, flag);

    gemm_mfma<F_BIAS | F_RELU><<<dim3(CDFF / 128, M / 128), 256, 0, stream>>>(
        x1, w1T, b1c, ffh, M, CDFF, CD);
    gemm_mfma<F_BIAS><<<dim3(CD / 128, M / 128), 256, 0, stream>>>(
        ffh, w2T, b2c, ffo, M, CD, CDFF);

    ln_kernel<<<dim3(M / 4), 256, 0, stream>>>(x1, ffo, g2c, be2c,
                                               (u16*)d_out, (float*)d_out, flag);
}